// Round 7
// baseline (517.440 us; speedup 1.0000x reference)
//
#include <hip/hip_runtime.h>

typedef _Float16 f16;
typedef f16   f16x2 __attribute__((ext_vector_type(2)));
typedef f16   f16x8 __attribute__((ext_vector_type(8)));
typedef __fp16 fp16x2 __attribute__((ext_vector_type(2)));
typedef float f32x4 __attribute__((ext_vector_type(4)));

#define NF 256      // features
#define NH 64       // hidden dim
#define NL 3        // hidden-to-hidden layers
#define WROWS 16    // batch rows per wave (1 subtile)
#define NWAVE 4
#define MT (WROWS * NWAVE)   // 64 rows per block
#define NTHR (NWAVE * 64)    // 256
#define WFRAG (NH * NH)

union F16x8u { f16x8 v; f16x2 h[4]; };

// f32-unit swizzled index into the h plane [MT][NH]; XOR flips col bits 2-4
// (16B units): keeps f32x4 chunks contiguous, spreads stride-256B rows.
__device__ __forceinline__ int hswz(int r, int c) {
    return r * NH + (c ^ ((r & 7) << 2));
}

// 2-elem fp16 hi/lo split via v_cvt_pkrtz (1 instr per packed pair):
// 3 VALU/elem and results are pre-packed for the MFMA fragment.
__device__ __forceinline__ void split2(float a, float b, f16x2& hi, f16x2& lo) {
    fp16x2 h = __builtin_amdgcn_cvt_pkrtz(a, b);
    fp16x2 l = __builtin_amdgcn_cvt_pkrtz(a - (float)h[0], b - (float)h[1]);
    hi = __builtin_bit_cast(f16x2, h);
    lo = __builtin_bit_cast(f16x2, l);
}

// ---- prepass: split Wh into f16 hi/lo fragment planes, laid out so the
// ---- main kernel's per-lane f16x8 load is fully coalesced (1KB/instr).
__global__ __launch_bounds__(256) void presplit_w(
    const float* __restrict__ Wh, f16* __restrict__ wsHi, f16* __restrict__ wsLo)
{
    __shared__ float wld[NH * NH];
    const int lf = blockIdx.x;            // l*NF + f
    const int t  = threadIdx.x;
    const float* __restrict__ src = Wh + (size_t)lf * WFRAG;
#pragma unroll
    for (int i = 0; i < 4; ++i)
        *(f32x4*)&wld[(i * 256 + t) * 4] = *(const f32x4*)&src[(i * 256 + t) * 4];
    __syncthreads();
#pragma unroll
    for (int g2 = 0; g2 < 2; ++g2) {
        const int g  = g2 * 256 + t;      // g = (nt*2+ks)*64 + ln
        const int ln = g & 63, ks = (g >> 6) & 1, nt = g >> 7;
        const int cl = ln & 15, gr = ln >> 4;
        f16x8 hi, lo;
#pragma unroll
        for (int jj = 0; jj < 8; ++jj) {
            const int k = ks * 32 + gr * 8 + jj;   // input-hidden index
            const int n = nt * 16 + cl;            // output-hidden index
            float v = wld[k * NH + n];
            f16 h = (f16)v;
            hi[jj] = h;
            lo[jj] = (f16)(v - (float)h);
        }
        const size_t dst = ((size_t)lf * 512 + g) * 8;
        *(f16x8*)&wsHi[dst] = hi;
        *(f16x8*)&wsLo[dst] = lo;
    }
}

template <bool PRE>
__global__ __launch_bounds__(NTHR, 6) void permlp_v6(
    const float* __restrict__ x,
    const float* __restrict__ W1,
    const float* __restrict__ b1,
    const float* __restrict__ Wh,
    const float* __restrict__ bh,
    const float* __restrict__ Wo,
    const float* __restrict__ bo,
    const f16* __restrict__ wsHi,
    const f16* __restrict__ wsLo,
    float* __restrict__ out,
    int nby)
{
    __shared__ float hbuf[MT * NH];   // 16 KB -> up to 8 blocks/CU

    // XCD-chunked bijective swizzle (nwg % 8 == 0): XCD i owns a contiguous
    // f-chunk with `by` varying fastest -> W working set L2-resident.
    const int nwg  = NF * nby;
    const int q    = nwg >> 3;
    const int bid  = blockIdx.x;
    const int wgid = (bid & 7) * q + (bid >> 3);
    const int f    = wgid / nby;
    const int by   = wgid - f * nby;

    const int tid = threadIdx.x;
    const int wv  = tid >> 6;
    const int ln  = tid & 63;
    const int cl  = ln & 15;
    const int gr  = ln >> 4;
    const int lr0 = wv * WROWS;
    const int gb0 = by * MT + lr0;

    // ---- hoist epilogue/output constants ----
    float biasv[NL][4];
#pragma unroll
    for (int l = 0; l < NL; ++l)
#pragma unroll
        for (int nt = 0; nt < 4; ++nt)
            biasv[l][nt] = bh[(size_t)(l * NF + f) * NH + nt * 16 + cl];
    float wov[4];
#pragma unroll
    for (int nt = 0; nt < 4; ++nt)
        wov[nt] = Wo[f * NH + nt * 16 + cl];
    const float bof = bo[f];

    // ---- layer 1: 4 lanes per row, 16 cols each; wave-private rows ----
    {
        const int r  = ln & 15;
        const int cg = ln >> 4;
        const float xv = x[(size_t)(gb0 + r) * NF + f];
        const float* __restrict__ w1 = W1 + f * NH + cg * 16;
        const float* __restrict__ bb = b1 + f * NH + cg * 16;
#pragma unroll
        for (int c4 = 0; c4 < 4; ++c4) {
            f32x4 w  = *(const f32x4*)&w1[c4 * 4];
            f32x4 bv = *(const f32x4*)&bb[c4 * 4];
            f32x4 v;
#pragma unroll
            for (int j = 0; j < 4; ++j)
                v[j] = fmaxf(fmaf(xv, w[j], bv[j]), 0.f);
            *(f32x4*)&hbuf[hswz(lr0 + r, cg * 16 + c4 * 4)] = v;
        }
    }
    // NO barriers anywhere: every wave touches only its own 16 rows.

    // ---- hidden layers; last layer fuses the output reduction ----
    for (int l = 0; l < NL; ++l) {
        // A-fragments: read f32 h, split hi/lo via cvt_pkrtz
        f16x8 ahi[2], alo[2];
#pragma unroll
        for (int ks = 0; ks < 2; ++ks) {
            const int k0 = ks * 32 + gr * 8;
            f32x4 a0 = *(const f32x4*)&hbuf[hswz(lr0 + cl, k0)];
            f32x4 a1 = *(const f32x4*)&hbuf[hswz(lr0 + cl, k0 + 4)];
            F16x8u hi8, lo8;
            split2(a0[0], a0[1], hi8.h[0], lo8.h[0]);
            split2(a0[2], a0[3], hi8.h[1], lo8.h[1]);
            split2(a1[0], a1[1], hi8.h[2], lo8.h[2]);
            split2(a1[2], a1[3], hi8.h[3], lo8.h[3]);
            ahi[ks] = hi8.v; alo[ks] = lo8.v;
        }

        f32x4 acc[4];
#pragma unroll
        for (int nt = 0; nt < 4; ++nt) {
            f32x4 z{0.f, 0.f, 0.f, 0.f};
            acc[nt] = z;
        }

        const f16* __restrict__ baseH = PRE ? wsHi + (size_t)(l * NF + f) * 4096 : nullptr;
        const f16* __restrict__ baseL = PRE ? wsLo + (size_t)(l * NF + f) * 4096 : nullptr;
        const float* __restrict__ Wl  = Wh + (size_t)(l * NF + f) * WFRAG;

#pragma unroll
        for (int nt = 0; nt < 4; ++nt)
#pragma unroll
            for (int ks = 0; ks < 2; ++ks) {
                f16x8 bhi8, blo8;
                if constexpr (PRE) {
                    const size_t off = (size_t)((nt * 2 + ks) * 64 + ln) * 8;
                    bhi8 = *(const f16x8*)&baseH[off];
                    blo8 = *(const f16x8*)&baseL[off];
                } else {
                    const int n  = nt * 16 + cl;
                    const int kb = ks * 32 + gr * 8;
                    const float* __restrict__ col = Wl + (size_t)kb * NH + n;
#pragma unroll
                    for (int j = 0; j < 8; ++j) {
                        float v = col[(size_t)j * NH];
                        f16 h = (f16)v;
                        bhi8[j] = h;
                        blo8[j] = (f16)(v - (float)h);
                    }
                }
                acc[nt] = __builtin_amdgcn_mfma_f32_16x16x32_f16(ahi[ks], bhi8, acc[nt], 0, 0, 0);
                acc[nt] = __builtin_amdgcn_mfma_f32_16x16x32_f16(alo[ks], bhi8, acc[nt], 0, 0, 0);
                acc[nt] = __builtin_amdgcn_mfma_f32_16x16x32_f16(ahi[ks], blo8, acc[nt], 0, 0, 0);
            }

        if (l < NL - 1) {
            // epilogue: store relu(acc + bias) back as f32 (post-relu h)
#pragma unroll
            for (int nt = 0; nt < 4; ++nt) {
                const float bb = biasv[l][nt];
#pragma unroll
                for (int i = 0; i < 4; ++i)
                    hbuf[hswz(lr0 + gr * 4 + i, nt * 16 + cl)] =
                        fmaxf(acc[nt][i] + bb, 0.f);
            }
        } else {
            // fused output layer straight from accumulators:
            // row gr*4+i lives across the 16 cl-lanes (4 cols each).
#pragma unroll
            for (int i = 0; i < 4; ++i) {
                float s = 0.f;
#pragma unroll
                for (int nt = 0; nt < 4; ++nt)
                    s = fmaf(fmaxf(acc[nt][i] + biasv[l][nt], 0.f), wov[nt], s);
                s += __shfl_xor(s, 1, 64);
                s += __shfl_xor(s, 2, 64);
                s += __shfl_xor(s, 4, 64);
                s += __shfl_xor(s, 8, 64);
                if (cl == 0)
                    atomicAdd(&out[gb0 + gr * 4 + i], s + bof);
            }
        }
    }
}

extern "C" void kernel_launch(void* const* d_in, const int* in_sizes, int n_in,
                              void* d_out, int out_size, void* d_ws, size_t ws_size,
                              hipStream_t stream)
{
    const float* x  = (const float*)d_in[0];
    const float* W1 = (const float*)d_in[1];
    const float* b1 = (const float*)d_in[2];
    const float* Wh = (const float*)d_in[3];
    const float* bh = (const float*)d_in[4];
    const float* Wo = (const float*)d_in[5];
    const float* bo = (const float*)d_in[6];
    float* out = (float*)d_out;

    const int B   = in_sizes[0] / NF;   // 16384
    const int nby = B / MT;             // 256

    hipMemsetAsync(out, 0, (size_t)out_size * sizeof(float), stream);

    const size_t planeElems = (size_t)NL * NF * WFRAG;          // 3.15M f16
    const size_t needW      = planeElems * 2 * sizeof(f16);     // ~12.6 MB
    dim3 grid(NF * nby);

    if (ws_size >= needW) {
        f16* wsHi = (f16*)d_ws;
        f16* wsLo = wsHi + planeElems;
        presplit_w<<<NL * NF, 256, 0, stream>>>(Wh, wsHi, wsLo);
        permlp_v6<true><<<grid, dim3(NTHR), 0, stream>>>(
            x, W1, b1, Wh, bh, Wo, bo, wsHi, wsLo, out, nby);
    } else {
        permlp_v6<false><<<grid, dim3(NTHR), 0, stream>>>(
            x, W1, b1, Wh, bh, Wo, bo, nullptr, nullptr, out, nby);
    }
}

// Round 8
// 376.723 us; speedup vs baseline: 1.3735x; 1.3735x over previous
//
#include <hip/hip_runtime.h>

typedef _Float16 f16;
typedef f16    f16x2 __attribute__((ext_vector_type(2)));
typedef f16    f16x4 __attribute__((ext_vector_type(4)));
typedef f16    f16x8 __attribute__((ext_vector_type(8)));
typedef __fp16 fp16x2 __attribute__((ext_vector_type(2)));
typedef float  f32x4 __attribute__((ext_vector_type(4)));

#define NF 256      // features
#define NH 64       // hidden dim
#define NL 3        // hidden-to-hidden layers
#define WROWS 32    // batch rows per wave (2 subtiles of 16)
#define NWAVE 4
#define MT (WROWS * NWAVE)   // 128 rows per block
#define NTHR (NWAVE * 64)    // 256
#define WFRAG (NH * NH)
#define ROWGR 9     // 16B granules per h-plane row: 8 data + 1 pad
                    // bank(granule) = 4*(r+g) mod 32 -> quarter-wave balanced,
                    // all h reads/writes <=2-way (free per m136). No XOR needed.

union U64 { f16x4 v4; f16x2 h[2]; };

// f16-unit index of granule g (0..7) in padded row r
__device__ __forceinline__ int hidx(int r, int g) { return (r * ROWGR + g) * 8; }

// 2-elem fp16 hi/lo split via v_cvt_pkrtz (results pre-packed for fragments)
__device__ __forceinline__ void split2(float a, float b, f16x2& hi, f16x2& lo) {
    fp16x2 h = __builtin_amdgcn_cvt_pkrtz(a, b);
    fp16x2 l = __builtin_amdgcn_cvt_pkrtz(a - (float)h[0], b - (float)h[1]);
    hi = __builtin_bit_cast(f16x2, h);
    lo = __builtin_bit_cast(f16x2, l);
}

// ---- prepass: split Wh into f16 hi/lo fragment planes (A-operand layout:
// ---- lane holds W^T[m=mt*16+cl][k=ks*32+gr*8+j]); coalesced f16x8 loads.
__global__ __launch_bounds__(256) void presplit_w(
    const float* __restrict__ Wh, f16* __restrict__ wsHi, f16* __restrict__ wsLo)
{
    __shared__ float wld[NH * NH];
    const int lf = blockIdx.x;            // l*NF + f
    const int t  = threadIdx.x;
    const float* __restrict__ src = Wh + (size_t)lf * WFRAG;
#pragma unroll
    for (int i = 0; i < 4; ++i)
        *(f32x4*)&wld[(i * 256 + t) * 4] = *(const f32x4*)&src[(i * 256 + t) * 4];
    __syncthreads();
#pragma unroll
    for (int g2 = 0; g2 < 2; ++g2) {
        const int g  = g2 * 256 + t;      // g = (mt*2+ks)*64 + ln
        const int ln = g & 63, ks = (g >> 6) & 1, mt = g >> 7;
        const int cl = ln & 15, gr = ln >> 4;
        f16x8 hi, lo;
#pragma unroll
        for (int jj = 0; jj < 8; ++jj) {
            const int k = ks * 32 + gr * 8 + jj;   // input-hidden index
            const int m = mt * 16 + cl;            // output-hidden index
            float v = wld[k * NH + m];             // W^T[m][k] = W[k][m]
            f16 h = (f16)v;
            hi[jj] = h;
            lo[jj] = (f16)(v - (float)h);
        }
        const size_t dst = ((size_t)lf * 512 + g) * 8;
        *(f16x8*)&wsHi[dst] = hi;
        *(f16x8*)&wsLo[dst] = lo;
    }
}

template <bool PRE>
__global__ __launch_bounds__(NTHR, 4) void permlp_v8(
    const float* __restrict__ x,
    const float* __restrict__ W1,
    const float* __restrict__ b1,
    const float* __restrict__ Wh,
    const float* __restrict__ bh,
    const float* __restrict__ Wo,
    const float* __restrict__ bo,
    const f16* __restrict__ wsHi,
    const f16* __restrict__ wsLo,
    float* __restrict__ out,
    int nby)
{
    // h planes: [MT rows][9 granules x 16B], hi + lo = 36 KB -> 4 blocks/CU
    __shared__ f16 hhi[MT * ROWGR * 8];
    __shared__ f16 hlo[MT * ROWGR * 8];

    // XCD-chunked bijective swizzle (nwg % 8 == 0): W working set L2-resident.
    const int nwg  = NF * nby;
    const int q    = nwg >> 3;
    const int bid  = blockIdx.x;
    const int wgid = (bid & 7) * q + (bid >> 3);
    const int f    = wgid / nby;
    const int by   = wgid - f * nby;

    const int tid = threadIdx.x;
    const int wv  = tid >> 6;
    const int ln  = tid & 63;
    const int cl  = ln & 15;
    const int gr  = ln >> 4;
    const int lr0 = wv * WROWS;
    const int gb0 = by * MT + lr0;

    // ---- layer 1: 2 lanes per row, 32 cols each; split+store f16 planes ----
    {
        const int r    = ln >> 1;
        const int half = ln & 1;
        const float xv = x[(size_t)(gb0 + r) * NF + f];
        const float* __restrict__ w1 = W1 + f * NH + half * 32;
        const float* __restrict__ bb = b1 + f * NH + half * 32;
        const int rr = lr0 + r;
#pragma unroll
        for (int c4 = 0; c4 < 8; ++c4) {
            const int cb = half * 32 + c4 * 4;
            f32x4 w  = *(const f32x4*)&w1[c4 * 4];
            f32x4 bv = *(const f32x4*)&bb[c4 * 4];
            U64 hi, lo;
            float v0 = fmaxf(fmaf(xv, w[0], bv[0]), 0.f);
            float v1 = fmaxf(fmaf(xv, w[1], bv[1]), 0.f);
            float v2 = fmaxf(fmaf(xv, w[2], bv[2]), 0.f);
            float v3 = fmaxf(fmaf(xv, w[3], bv[3]), 0.f);
            split2(v0, v1, hi.h[0], lo.h[0]);
            split2(v2, v3, hi.h[1], lo.h[1]);
            const int base = hidx(rr, cb >> 3) + (cb & 7);   // (cb&7) = 0 or 4
            *(f16x4*)&hhi[base] = hi.v4;
            *(f16x4*)&hlo[base] = lo.v4;
        }
    }
    // NO barriers anywhere: every wave touches only its own 32 rows.

    const float bof = bo[f];
    float souts[2] = {0.f, 0.f};

    for (int l = 0; l < NL; ++l) {
        // B-fragments = h^T: lane: col(batch)=cl, k(n_in)=ks*32+gr*8+j
        // -> one ds_read_b128 per plane, fragment-native, zero repack.
        f16x8 Bhi[2][2], Blo[2][2];   // [st][ks]
#pragma unroll
        for (int st = 0; st < 2; ++st) {
            const int r = lr0 + st * 16 + cl;
#pragma unroll
            for (int ks = 0; ks < 2; ++ks) {
                Bhi[st][ks] = *(const f16x8*)&hhi[hidx(r, ks * 4 + gr)];
                Blo[st][ks] = *(const f16x8*)&hlo[hidx(r, ks * 4 + gr)];
            }
        }

        const f16* __restrict__ baseH = PRE ? wsHi + (size_t)(l * NF + f) * 4096 : nullptr;
        const f16* __restrict__ baseL = PRE ? wsLo + (size_t)(l * NF + f) * 4096 : nullptr;
        const float* __restrict__ Wl  = Wh + (size_t)(l * NF + f) * WFRAG;
        const float* __restrict__ bl  = bh + (size_t)(l * NF + f) * NH;
        const bool last = (l == NL - 1);

#pragma unroll
        for (int mt = 0; mt < 4; ++mt) {
            // A-fragments = W^T tile mt (streamed through 16 VGPRs)
            f16x8 Ahi[2], Alo[2];
#pragma unroll
            for (int ks = 0; ks < 2; ++ks) {
                if constexpr (PRE) {
                    const size_t off = (size_t)((mt * 2 + ks) * 64 + ln) * 8;
                    Ahi[ks] = *(const f16x8*)&baseH[off];
                    Alo[ks] = *(const f16x8*)&baseL[off];
                } else {
                    const int m  = mt * 16 + cl;
                    const int kb = ks * 32 + gr * 8;
                    const float* __restrict__ col = Wl + (size_t)kb * NH + m;
                    f16x8 hi8, lo8;
#pragma unroll
                    for (int j = 0; j < 8; ++j) {
                        float v = col[(size_t)j * NH];
                        f16 h = (f16)v;
                        hi8[j] = h;
                        lo8[j] = (f16)(v - (float)h);
                    }
                    Ahi[ks] = hi8; Alo[ks] = lo8;
                }
            }

            f32x4 acc0{0.f, 0.f, 0.f, 0.f};
            f32x4 acc1{0.f, 0.f, 0.f, 0.f};
#pragma unroll
            for (int ks = 0; ks < 2; ++ks) {
                acc0 = __builtin_amdgcn_mfma_f32_16x16x32_f16(Ahi[ks], Bhi[0][ks], acc0, 0, 0, 0);
                acc1 = __builtin_amdgcn_mfma_f32_16x16x32_f16(Ahi[ks], Bhi[1][ks], acc1, 0, 0, 0);
                acc0 = __builtin_amdgcn_mfma_f32_16x16x32_f16(Ahi[ks], Blo[0][ks], acc0, 0, 0, 0);
                acc1 = __builtin_amdgcn_mfma_f32_16x16x32_f16(Ahi[ks], Blo[1][ks], acc1, 0, 0, 0);
                acc0 = __builtin_amdgcn_mfma_f32_16x16x32_f16(Alo[ks], Bhi[0][ks], acc0, 0, 0, 0);
                acc1 = __builtin_amdgcn_mfma_f32_16x16x32_f16(Alo[ks], Bhi[1][ks], acc1, 0, 0, 0);
            }

            // C tile: lane holds batch=cl, n_out = mt*16 + gr*4 + i  (i=0..3)
            const f32x4 bias4 = *(const f32x4*)&bl[mt * 16 + gr * 4];
            if (!last) {
                const int g   = mt * 2 + (gr >> 1);
                const int off = (gr & 1) * 4;
#pragma unroll
                for (int st = 0; st < 2; ++st) {
                    const f32x4 a = st ? acc1 : acc0;
                    float v0 = fmaxf(a[0] + bias4[0], 0.f);
                    float v1 = fmaxf(a[1] + bias4[1], 0.f);
                    float v2 = fmaxf(a[2] + bias4[2], 0.f);
                    float v3 = fmaxf(a[3] + bias4[3], 0.f);
                    U64 hi, lo;
                    split2(v0, v1, hi.h[0], lo.h[0]);
                    split2(v2, v3, hi.h[1], lo.h[1]);
                    const int base = hidx(lr0 + st * 16 + cl, g) + off;
                    *(f16x4*)&hhi[base] = hi.v4;
                    *(f16x4*)&hlo[base] = lo.v4;
                }
            } else {
                // fused output layer: dot with Wo straight from accumulators
                const f32x4 wov4 = *(const f32x4*)&Wo[f * NH + mt * 16 + gr * 4];
#pragma unroll
                for (int st = 0; st < 2; ++st) {
                    const f32x4 a = st ? acc1 : acc0;
                    float s = souts[st];
#pragma unroll
                    for (int i = 0; i < 4; ++i)
                        s = fmaf(fmaxf(a[i] + bias4[i], 0.f), wov4[i], s);
                    souts[st] = s;
                }
            }
        }
    }

    // ---- commit: reduce over the 4 gr-groups (64 hidden), one atomic/row ----
#pragma unroll
    for (int st = 0; st < 2; ++st) {
        float s = souts[st];
        s += __shfl_xor(s, 16, 64);
        s += __shfl_xor(s, 32, 64);
        if (ln < 16)
            atomicAdd(&out[gb0 + st * 16 + cl], s + bof);
    }
}

extern "C" void kernel_launch(void* const* d_in, const int* in_sizes, int n_in,
                              void* d_out, int out_size, void* d_ws, size_t ws_size,
                              hipStream_t stream)
{
    const float* x  = (const float*)d_in[0];
    const float* W1 = (const float*)d_in[1];
    const float* b1 = (const float*)d_in[2];
    const float* Wh = (const float*)d_in[3];
    const float* bh = (const float*)d_in[4];
    const float* Wo = (const float*)d_in[5];
    const float* bo = (const float*)d_in[6];
    float* out = (float*)d_out;

    const int B   = in_sizes[0] / NF;   // 16384
    const int nby = B / MT;             // 128

    hipMemsetAsync(out, 0, (size_t)out_size * sizeof(float), stream);

    const size_t planeElems = (size_t)NL * NF * WFRAG;          // 3.15M f16
    const size_t needW      = planeElems * 2 * sizeof(f16);     // ~12.6 MB
    dim3 grid(NF * nby);

    if (ws_size >= needW) {
        f16* wsHi = (f16*)d_ws;
        f16* wsLo = wsHi + planeElems;
        presplit_w<<<NL * NF, 256, 0, stream>>>(Wh, wsHi, wsLo);
        permlp_v8<true><<<grid, dim3(NTHR), 0, stream>>>(
            x, W1, b1, Wh, bh, Wo, bo, wsHi, wsLo, out, nby);
    } else {
        permlp_v8<false><<<grid, dim3(NTHR), 0, stream>>>(
            x, W1, b1, Wh, bh, Wo, bo, nullptr, nullptr, out, nby);
    }
}

// Round 9
// 343.695 us; speedup vs baseline: 1.5055x; 1.0961x over previous
//
#include <hip/hip_runtime.h>

typedef _Float16 f16;
typedef f16    f16x2 __attribute__((ext_vector_type(2)));
typedef f16    f16x8 __attribute__((ext_vector_type(8)));
typedef __fp16 fp16x2 __attribute__((ext_vector_type(2)));
typedef float  f32x4 __attribute__((ext_vector_type(4)));

#define NF 256      // features
#define NH 64       // hidden dim
#define NL 3        // hidden-to-hidden layers
#define NB 2        // 16-row batch tiles per wave -> 32 rows/wave
#define NWAVE 4
#define MT (NB * 16 * NWAVE)   // 128 rows per block
#define NTHR (NWAVE * 64)      // 256
#define WFRAG (NH * NH)

union U2 { f16x8 v8; f16x2 h[4]; };

// input-side hidden-unit permutation baked into W staging:
// sigma(p = 32ks + 8gr + j) = 32ks + 16*(j>>2) + 4gr + (j&3)
// With this, the MFMA C-tile (col=batch=cl, row=16mt+4gr+i), packed pairwise,
// IS the next layer's B-fragment: h never leaves registers.

// 2-elem fp16 hi/lo split via v_cvt_pkrtz (results pre-packed for fragments)
__device__ __forceinline__ void split2(float a, float b, f16x2& hi, f16x2& lo) {
    fp16x2 h = __builtin_amdgcn_cvt_pkrtz(a, b);
    fp16x2 l = __builtin_amdgcn_cvt_pkrtz(a - (float)h[0], b - (float)h[1]);
    hi = __builtin_bit_cast(f16x2, h);
    lo = __builtin_bit_cast(f16x2, l);
}

// ---- prepass: split Wh into f16 hi/lo A-fragment planes with the sigma
// ---- permutation baked into the k side; coalesced f16x8 loads in main.
__global__ __launch_bounds__(256) void presplit_w(
    const float* __restrict__ Wh, f16* __restrict__ wsHi, f16* __restrict__ wsLo)
{
    __shared__ float wld[NH * NH];
    const int lf = blockIdx.x;            // l*NF + f
    const int t  = threadIdx.x;
    const float* __restrict__ src = Wh + (size_t)lf * WFRAG;
#pragma unroll
    for (int i = 0; i < 4; ++i)
        *(f32x4*)&wld[(i * 256 + t) * 4] = *(const f32x4*)&src[(i * 256 + t) * 4];
    __syncthreads();
#pragma unroll
    for (int g2 = 0; g2 < 2; ++g2) {
        const int g  = g2 * 256 + t;      // g = (mt*2+ks)*64 + ln
        const int ln = g & 63, ks = (g >> 6) & 1, mt = g >> 7;
        const int cl = ln & 15, gr = ln >> 4;
        const int m  = mt * 16 + cl;      // output unit (natural order)
        f16x8 hi, lo;
#pragma unroll
        for (int jj = 0; jj < 8; ++jj) {
            const int u = 32 * ks + 16 * (jj >> 2) + 4 * gr + (jj & 3);  // sigma
            float v = wld[u * NH + m];    // W[u][m]
            f16 h = (f16)v;
            hi[jj] = h;
            lo[jj] = (f16)(v - (float)h);
        }
        const size_t dst = ((size_t)lf * 512 + g) * 8;
        *(f16x8*)&wsHi[dst] = hi;
        *(f16x8*)&wsLo[dst] = lo;
    }
}

template <bool PRE>
__global__ __launch_bounds__(NTHR, 4) void permlp_v9(
    const float* __restrict__ x,
    const float* __restrict__ W1,
    const float* __restrict__ b1,
    const float* __restrict__ Wh,
    const float* __restrict__ bh,
    const float* __restrict__ Wo,
    const float* __restrict__ bo,
    const f16* __restrict__ wsHi,
    const f16* __restrict__ wsLo,
    float* __restrict__ out,
    int nby)
{
    // XCD-chunked bijective swizzle (nwg % 8 == 0): W working set L2-resident.
    const int nwg  = NF * nby;
    const int q    = nwg >> 3;
    const int bid  = blockIdx.x;
    const int wgid = (bid & 7) * q + (bid >> 3);
    const int f    = wgid / nby;
    const int by   = wgid - f * nby;

    const int tid = threadIdx.x;
    const int wv  = tid >> 6;
    const int ln  = tid & 63;
    const int cl  = ln & 15;
    const int gr  = ln >> 4;
    const int gb0 = by * MT + wv * (NB * 16);

    // ---- layer 1 straight into registers (sigma-ordered B-fragments) ----
    U2 HAhi[NB][2], HAlo[NB][2], HBhi[NB][2], HBlo[NB][2];
    {
        float xv[NB];
#pragma unroll
        for (int bt = 0; bt < NB; ++bt)
            xv[bt] = x[(size_t)(gb0 + bt * 16 + cl) * NF + f];
        const float* __restrict__ w1 = W1 + f * NH;
        const float* __restrict__ bb = b1 + f * NH;
#pragma unroll
        for (int ks = 0; ks < 2; ++ks)
#pragma unroll
            for (int jq = 0; jq < 2; ++jq) {
                const int ub = 32 * ks + 16 * jq + 4 * gr;   // sigma-ordered
                const f32x4 w4 = *(const f32x4*)&w1[ub];
                const f32x4 b4 = *(const f32x4*)&bb[ub];
#pragma unroll
                for (int bt = 0; bt < NB; ++bt) {
                    float v0 = fmaxf(fmaf(xv[bt], w4[0], b4[0]), 0.f);
                    float v1 = fmaxf(fmaf(xv[bt], w4[1], b4[1]), 0.f);
                    float v2 = fmaxf(fmaf(xv[bt], w4[2], b4[2]), 0.f);
                    float v3 = fmaxf(fmaf(xv[bt], w4[3], b4[3]), 0.f);
                    split2(v0, v1, HAhi[bt][ks].h[jq * 2],     HAlo[bt][ks].h[jq * 2]);
                    split2(v2, v3, HAhi[bt][ks].h[jq * 2 + 1], HAlo[bt][ks].h[jq * 2 + 1]);
                }
            }
    }

    // ---- one hidden layer: I regs -> O regs, all in fragment layout ----
    auto hidden = [&](U2 (&Ihi)[NB][2], U2 (&Ilo)[NB][2],
                      U2 (&Ohi)[NB][2], U2 (&Olo)[NB][2], const int l) {
        const f16* __restrict__ baseH = PRE ? wsHi + (size_t)(l * NF + f) * 4096 : nullptr;
        const f16* __restrict__ baseL = PRE ? wsLo + (size_t)(l * NF + f) * 4096 : nullptr;
        const float* __restrict__ Wl  = Wh + (size_t)(l * NF + f) * WFRAG;
        const float* __restrict__ bl  = bh + (size_t)(l * NF + f) * NH;
#pragma unroll
        for (int mt = 0; mt < 4; ++mt) {
            f16x8 Ahi[2], Alo[2];
#pragma unroll
            for (int ks = 0; ks < 2; ++ks) {
                if constexpr (PRE) {
                    const size_t off = (size_t)((mt * 2 + ks) * 64 + ln) * 8;
                    Ahi[ks] = *(const f16x8*)&baseH[off];
                    Alo[ks] = *(const f16x8*)&baseL[off];
                } else {
                    const int m = mt * 16 + cl;
                    f16x8 hi8, lo8;
#pragma unroll
                    for (int j = 0; j < 8; ++j) {
                        const int u = 32 * ks + 16 * (j >> 2) + 4 * gr + (j & 3);
                        float v = Wl[(size_t)u * NH + m];
                        f16 h = (f16)v;
                        hi8[j] = h;
                        lo8[j] = (f16)(v - (float)h);
                    }
                    Ahi[ks] = hi8; Alo[ks] = lo8;
                }
            }
            f32x4 acc[NB];
#pragma unroll
            for (int bt = 0; bt < NB; ++bt) {
                f32x4 z{0.f, 0.f, 0.f, 0.f};
                acc[bt] = z;
            }
#pragma unroll
            for (int ks = 0; ks < 2; ++ks)
#pragma unroll
                for (int bt = 0; bt < NB; ++bt) {
                    acc[bt] = __builtin_amdgcn_mfma_f32_16x16x32_f16(Ahi[ks], Ihi[bt][ks].v8, acc[bt], 0, 0, 0);
                    acc[bt] = __builtin_amdgcn_mfma_f32_16x16x32_f16(Ahi[ks], Ilo[bt][ks].v8, acc[bt], 0, 0, 0);
                    acc[bt] = __builtin_amdgcn_mfma_f32_16x16x32_f16(Alo[ks], Ihi[bt][ks].v8, acc[bt], 0, 0, 0);
                }
            // C tile: lane holds batch=cl, units mt*16+gr*4+i; pack into the
            // next layer's fragment slots: O[bt][mt>>1] words (mt&1)*2 + {0,1}
            const f32x4 bias4 = *(const f32x4*)&bl[mt * 16 + gr * 4];
#pragma unroll
            for (int bt = 0; bt < NB; ++bt) {
                float v0 = fmaxf(acc[bt][0] + bias4[0], 0.f);
                float v1 = fmaxf(acc[bt][1] + bias4[1], 0.f);
                float v2 = fmaxf(acc[bt][2] + bias4[2], 0.f);
                float v3 = fmaxf(acc[bt][3] + bias4[3], 0.f);
                split2(v0, v1, Ohi[bt][mt >> 1].h[(mt & 1) * 2],     Olo[bt][mt >> 1].h[(mt & 1) * 2]);
                split2(v2, v3, Ohi[bt][mt >> 1].h[(mt & 1) * 2 + 1], Olo[bt][mt >> 1].h[(mt & 1) * 2 + 1]);
            }
        }
    };

    hidden(HAhi, HAlo, HBhi, HBlo, 0);
    hidden(HBhi, HBlo, HAhi, HAlo, 1);

    // ---- last hidden layer with fused output dot (reads HA) ----
    float souts[NB] = {0.f, 0.f};
    {
        const int l = NL - 1;
        const f16* __restrict__ baseH = PRE ? wsHi + (size_t)(l * NF + f) * 4096 : nullptr;
        const f16* __restrict__ baseL = PRE ? wsLo + (size_t)(l * NF + f) * 4096 : nullptr;
        const float* __restrict__ Wl  = Wh + (size_t)(l * NF + f) * WFRAG;
        const float* __restrict__ bl  = bh + (size_t)(l * NF + f) * NH;
#pragma unroll
        for (int mt = 0; mt < 4; ++mt) {
            f16x8 Ahi[2], Alo[2];
#pragma unroll
            for (int ks = 0; ks < 2; ++ks) {
                if constexpr (PRE) {
                    const size_t off = (size_t)((mt * 2 + ks) * 64 + ln) * 8;
                    Ahi[ks] = *(const f16x8*)&baseH[off];
                    Alo[ks] = *(const f16x8*)&baseL[off];
                } else {
                    const int m = mt * 16 + cl;
                    f16x8 hi8, lo8;
#pragma unroll
                    for (int j = 0; j < 8; ++j) {
                        const int u = 32 * ks + 16 * (j >> 2) + 4 * gr + (j & 3);
                        float v = Wl[(size_t)u * NH + m];
                        f16 h = (f16)v;
                        hi8[j] = h;
                        lo8[j] = (f16)(v - (float)h);
                    }
                    Ahi[ks] = hi8; Alo[ks] = lo8;
                }
            }
            f32x4 acc[NB];
#pragma unroll
            for (int bt = 0; bt < NB; ++bt) {
                f32x4 z{0.f, 0.f, 0.f, 0.f};
                acc[bt] = z;
            }
#pragma unroll
            for (int ks = 0; ks < 2; ++ks)
#pragma unroll
                for (int bt = 0; bt < NB; ++bt) {
                    acc[bt] = __builtin_amdgcn_mfma_f32_16x16x32_f16(Ahi[ks], HAhi[bt][ks].v8, acc[bt], 0, 0, 0);
                    acc[bt] = __builtin_amdgcn_mfma_f32_16x16x32_f16(Ahi[ks], HAlo[bt][ks].v8, acc[bt], 0, 0, 0);
                    acc[bt] = __builtin_amdgcn_mfma_f32_16x16x32_f16(Alo[ks], HAhi[bt][ks].v8, acc[bt], 0, 0, 0);
                }
            const f32x4 bias4 = *(const f32x4*)&bl[mt * 16 + gr * 4];
            const f32x4 wov4  = *(const f32x4*)&Wo[f * NH + mt * 16 + gr * 4];
#pragma unroll
            for (int bt = 0; bt < NB; ++bt)
#pragma unroll
                for (int i = 0; i < 4; ++i)
                    souts[bt] = fmaf(fmaxf(acc[bt][i] + bias4[i], 0.f), wov4[i], souts[bt]);
        }
    }

    // ---- commit: reduce over gr-groups, one atomic per row ----
    const float bof = bo[f];
#pragma unroll
    for (int bt = 0; bt < NB; ++bt) {
        float s = souts[bt];
        s += __shfl_xor(s, 16, 64);
        s += __shfl_xor(s, 32, 64);
        if (ln < 16)
            atomicAdd(&out[gb0 + bt * 16 + ln], s + bof);
    }
}

extern "C" void kernel_launch(void* const* d_in, const int* in_sizes, int n_in,
                              void* d_out, int out_size, void* d_ws, size_t ws_size,
                              hipStream_t stream)
{
    const float* x  = (const float*)d_in[0];
    const float* W1 = (const float*)d_in[1];
    const float* b1 = (const float*)d_in[2];
    const float* Wh = (const float*)d_in[3];
    const float* bh = (const float*)d_in[4];
    const float* Wo = (const float*)d_in[5];
    const float* bo = (const float*)d_in[6];
    float* out = (float*)d_out;

    const int B   = in_sizes[0] / NF;   // 16384
    const int nby = B / MT;             // 128

    hipMemsetAsync(out, 0, (size_t)out_size * sizeof(float), stream);

    const size_t planeElems = (size_t)NL * NF * WFRAG;          // 3.15M f16
    const size_t needW      = planeElems * 2 * sizeof(f16);     // ~12.6 MB
    dim3 grid(NF * nby);

    if (ws_size >= needW) {
        f16* wsHi = (f16*)d_ws;
        f16* wsLo = wsHi + planeElems;
        presplit_w<<<NL * NF, 256, 0, stream>>>(Wh, wsHi, wsLo);
        permlp_v9<true><<<grid, dim3(NTHR), 0, stream>>>(
            x, W1, b1, Wh, bh, Wo, bo, wsHi, wsLo, out, nby);
    } else {
        permlp_v9<false><<<grid, dim3(NTHR), 0, stream>>>(
            x, W1, b1, Wh, bh, Wo, bo, nullptr, nullptr, out, nby);
    }
}

// Round 10
// 209.825 us; speedup vs baseline: 2.4661x; 1.6380x over previous
//
#include <hip/hip_runtime.h>

typedef _Float16 f16;
typedef f16    f16x2 __attribute__((ext_vector_type(2)));
typedef f16    f16x8 __attribute__((ext_vector_type(8)));
typedef float  f32x4 __attribute__((ext_vector_type(4)));

#define NF 256      // features
#define NH 64       // hidden dim
#define NL 3        // hidden-to-hidden layers
#define NB 4        // 16-row batch tiles per wave -> 64 rows/wave
#define NWAVE 4
#define MT (NB * 16 * NWAVE)   // 256 rows per block
#define NTHR (NWAVE * 64)      // 256
#define WFRAG (NH * NH)

union U2 { f16x8 v8; f16x2 h[4]; };

// input-side hidden-unit permutation baked into W staging:
// sigma(p = 32ks + 8gr + j) = 32ks + 16*(j>>2) + 4gr + (j&3)
// With this, the MFMA C-tile (col=batch=cl, row=16mt+4gr+i), packed pairwise,
// IS the next layer's B-fragment: h never leaves registers (verified r9).
//
// Numerics (2-term): W split exactly as whi+wlo (prepass, err ~2^-22);
// h rounded once to f16 RTN (rel err 2^-12). acc = whi*h + wlo*h in fp32.
// Hidden layers are contractive (||W|| ~ 0.6) -> final absmax ~5e-3 < 2.1e-2.

// ---- prepass: split Wh into f16 hi/lo A-fragment planes with the sigma
// ---- permutation baked into the k side; coalesced f16x8 loads in main.
__global__ __launch_bounds__(256) void presplit_w(
    const float* __restrict__ Wh, f16* __restrict__ wsHi, f16* __restrict__ wsLo)
{
    __shared__ float wld[NH * NH];
    const int lf = blockIdx.x;            // l*NF + f
    const int t  = threadIdx.x;
    const float* __restrict__ src = Wh + (size_t)lf * WFRAG;
#pragma unroll
    for (int i = 0; i < 4; ++i)
        *(f32x4*)&wld[(i * 256 + t) * 4] = *(const f32x4*)&src[(i * 256 + t) * 4];
    __syncthreads();
#pragma unroll
    for (int g2 = 0; g2 < 2; ++g2) {
        const int g  = g2 * 256 + t;      // g = (mt*2+ks)*64 + ln
        const int ln = g & 63, ks = (g >> 6) & 1, mt = g >> 7;
        const int cl = ln & 15, gr = ln >> 4;
        const int m  = mt * 16 + cl;      // output unit (natural order)
        f16x8 hi, lo;
#pragma unroll
        for (int jj = 0; jj < 8; ++jj) {
            const int u = 32 * ks + 16 * (jj >> 2) + 4 * gr + (jj & 3);  // sigma
            float v = wld[u * NH + m];    // W[u][m]
            f16 h = (f16)v;
            hi[jj] = h;
            lo[jj] = (f16)(v - (float)h);
        }
        const size_t dst = ((size_t)lf * 512 + g) * 8;
        *(f16x8*)&wsHi[dst] = hi;
        *(f16x8*)&wsLo[dst] = lo;
    }
}

template <bool PRE>
__global__ __launch_bounds__(NTHR, 4) void permlp_v10(
    const float* __restrict__ x,
    const float* __restrict__ W1,
    const float* __restrict__ b1,
    const float* __restrict__ Wh,
    const float* __restrict__ bh,
    const float* __restrict__ Wo,
    const float* __restrict__ bo,
    const f16* __restrict__ wsHi,
    const f16* __restrict__ wsLo,
    float* __restrict__ out,
    int nby)
{
    // XCD-chunked bijective swizzle (nwg % 8 == 0): W working set L2-resident.
    const int nwg  = NF * nby;
    const int q    = nwg >> 3;
    const int bid  = blockIdx.x;
    const int wgid = (bid & 7) * q + (bid >> 3);
    const int f    = wgid / nby;
    const int by   = wgid - f * nby;

    const int tid = threadIdx.x;
    const int wv  = tid >> 6;
    const int ln  = tid & 63;
    const int cl  = ln & 15;
    const int gr  = ln >> 4;
    const int gb0 = by * MT + wv * (NB * 16);

    // ---- layer 1 straight into registers (sigma-ordered B-fragments) ----
    U2 HA[NB][2], HB[NB][2];   // single f16 plane (RTN)
    {
        float xv[NB];
#pragma unroll
        for (int bt = 0; bt < NB; ++bt)
            xv[bt] = x[(size_t)(gb0 + bt * 16 + cl) * NF + f];
        const float* __restrict__ w1 = W1 + f * NH;
        const float* __restrict__ bb = b1 + f * NH;
#pragma unroll
        for (int ks = 0; ks < 2; ++ks)
#pragma unroll
            for (int jq = 0; jq < 2; ++jq) {
                const int ub = 32 * ks + 16 * jq + 4 * gr;   // sigma-ordered
                const f32x4 w4 = *(const f32x4*)&w1[ub];
                const f32x4 b4 = *(const f32x4*)&bb[ub];
#pragma unroll
                for (int bt = 0; bt < NB; ++bt) {
                    float v0 = fmaxf(fmaf(xv[bt], w4[0], b4[0]), 0.f);
                    float v1 = fmaxf(fmaf(xv[bt], w4[1], b4[1]), 0.f);
                    float v2 = fmaxf(fmaf(xv[bt], w4[2], b4[2]), 0.f);
                    float v3 = fmaxf(fmaf(xv[bt], w4[3], b4[3]), 0.f);
                    HA[bt][ks].h[jq * 2]     = f16x2{(f16)v0, (f16)v1};  // RTN
                    HA[bt][ks].h[jq * 2 + 1] = f16x2{(f16)v2, (f16)v3};
                }
            }
    }

    // ---- one hidden layer: I regs -> O regs, all in fragment layout ----
    auto hidden = [&](U2 (&I)[NB][2], U2 (&O)[NB][2], const int l) {
        const f16* __restrict__ baseH = PRE ? wsHi + (size_t)(l * NF + f) * 4096 : nullptr;
        const f16* __restrict__ baseL = PRE ? wsLo + (size_t)(l * NF + f) * 4096 : nullptr;
        const float* __restrict__ Wl  = Wh + (size_t)(l * NF + f) * WFRAG;
        const float* __restrict__ bl  = bh + (size_t)(l * NF + f) * NH;
#pragma unroll
        for (int mt = 0; mt < 4; ++mt) {
            f16x8 Ahi[2], Alo[2];
#pragma unroll
            for (int ks = 0; ks < 2; ++ks) {
                if constexpr (PRE) {
                    const size_t off = (size_t)((mt * 2 + ks) * 64 + ln) * 8;
                    Ahi[ks] = *(const f16x8*)&baseH[off];
                    Alo[ks] = *(const f16x8*)&baseL[off];
                } else {
                    const int m = mt * 16 + cl;
                    f16x8 hi8, lo8;
#pragma unroll
                    for (int j = 0; j < 8; ++j) {
                        const int u = 32 * ks + 16 * (j >> 2) + 4 * gr + (j & 3);
                        float v = Wl[(size_t)u * NH + m];
                        f16 h = (f16)v;
                        hi8[j] = h;
                        lo8[j] = (f16)(v - (float)h);
                    }
                    Ahi[ks] = hi8; Alo[ks] = lo8;
                }
            }
            // bias pre-loaded into the accumulator (saves the epilogue add)
            const f32x4 bias4 = *(const f32x4*)&bl[mt * 16 + gr * 4];
            f32x4 acc[NB];
#pragma unroll
            for (int bt = 0; bt < NB; ++bt) acc[bt] = bias4;
#pragma unroll
            for (int ks = 0; ks < 2; ++ks)
#pragma unroll
                for (int bt = 0; bt < NB; ++bt) {
                    acc[bt] = __builtin_amdgcn_mfma_f32_16x16x32_f16(Alo[ks], I[bt][ks].v8, acc[bt], 0, 0, 0);
                    acc[bt] = __builtin_amdgcn_mfma_f32_16x16x32_f16(Ahi[ks], I[bt][ks].v8, acc[bt], 0, 0, 0);
                }
            // C tile: lane holds batch=cl, units mt*16+gr*4+i; pack into the
            // next layer's fragment slots: O[bt][mt>>1] elements (mt&1)*4+i
#pragma unroll
            for (int bt = 0; bt < NB; ++bt) {
                float v0 = fmaxf(acc[bt][0], 0.f);
                float v1 = fmaxf(acc[bt][1], 0.f);
                float v2 = fmaxf(acc[bt][2], 0.f);
                float v3 = fmaxf(acc[bt][3], 0.f);
                O[bt][mt >> 1].h[(mt & 1) * 2]     = f16x2{(f16)v0, (f16)v1};
                O[bt][mt >> 1].h[(mt & 1) * 2 + 1] = f16x2{(f16)v2, (f16)v3};
            }
        }
    };

    hidden(HA, HB, 0);
    hidden(HB, HA, 1);

    // ---- last hidden layer with fused output dot (reads HA) ----
    float souts[NB] = {0.f, 0.f, 0.f, 0.f};
    {
        const int l = NL - 1;
        const f16* __restrict__ baseH = PRE ? wsHi + (size_t)(l * NF + f) * 4096 : nullptr;
        const f16* __restrict__ baseL = PRE ? wsLo + (size_t)(l * NF + f) * 4096 : nullptr;
        const float* __restrict__ Wl  = Wh + (size_t)(l * NF + f) * WFRAG;
        const float* __restrict__ bl  = bh + (size_t)(l * NF + f) * NH;
#pragma unroll
        for (int mt = 0; mt < 4; ++mt) {
            f16x8 Ahi[2], Alo[2];
#pragma unroll
            for (int ks = 0; ks < 2; ++ks) {
                if constexpr (PRE) {
                    const size_t off = (size_t)((mt * 2 + ks) * 64 + ln) * 8;
                    Ahi[ks] = *(const f16x8*)&baseH[off];
                    Alo[ks] = *(const f16x8*)&baseL[off];
                } else {
                    const int m = mt * 16 + cl;
                    f16x8 hi8, lo8;
#pragma unroll
                    for (int j = 0; j < 8; ++j) {
                        const int u = 32 * ks + 16 * (j >> 2) + 4 * gr + (j & 3);
                        float v = Wl[(size_t)u * NH + m];
                        f16 h = (f16)v;
                        hi8[j] = h;
                        lo8[j] = (f16)(v - (float)h);
                    }
                    Ahi[ks] = hi8; Alo[ks] = lo8;
                }
            }
            const f32x4 bias4 = *(const f32x4*)&bl[mt * 16 + gr * 4];
            f32x4 acc[NB];
#pragma unroll
            for (int bt = 0; bt < NB; ++bt) acc[bt] = bias4;
#pragma unroll
            for (int ks = 0; ks < 2; ++ks)
#pragma unroll
                for (int bt = 0; bt < NB; ++bt) {
                    acc[bt] = __builtin_amdgcn_mfma_f32_16x16x32_f16(Alo[ks], HA[bt][ks].v8, acc[bt], 0, 0, 0);
                    acc[bt] = __builtin_amdgcn_mfma_f32_16x16x32_f16(Ahi[ks], HA[bt][ks].v8, acc[bt], 0, 0, 0);
                }
            const f32x4 wov4 = *(const f32x4*)&Wo[f * NH + mt * 16 + gr * 4];
#pragma unroll
            for (int bt = 0; bt < NB; ++bt)
#pragma unroll
                for (int i = 0; i < 4; ++i)
                    souts[bt] = fmaf(fmaxf(acc[bt][i], 0.f), wov4[i], souts[bt]);
        }
    }

    // ---- commit: reduce over gr-groups, one atomic per row ----
    const float bof = bo[f];
#pragma unroll
    for (int bt = 0; bt < NB; ++bt) {
        float s = souts[bt];
        s += __shfl_xor(s, 16, 64);
        s += __shfl_xor(s, 32, 64);
        if (ln < 16)
            atomicAdd(&out[gb0 + bt * 16 + ln], s + bof);
    }
}

extern "C" void kernel_launch(void* const* d_in, const int* in_sizes, int n_in,
                              void* d_out, int out_size, void* d_ws, size_t ws_size,
                              hipStream_t stream)
{
    const float* x  = (const float*)d_in[0];
    const float* W1 = (const float*)d_in[1];
    const float* b1 = (const float*)d_in[2];
    const float* Wh = (const float*)d_in[3];
    const float* bh = (const float*)d_in[4];
    const float* Wo = (const float*)d_in[5];
    const float* bo = (const float*)d_in[6];
    float* out = (float*)d_out;

    const int B   = in_sizes[0] / NF;   // 16384
    const int nby = B / MT;             // 64

    hipMemsetAsync(out, 0, (size_t)out_size * sizeof(float), stream);

    const size_t planeElems = (size_t)NL * NF * WFRAG;          // 3.15M f16
    const size_t needW      = planeElems * 2 * sizeof(f16);     // ~12.6 MB
    dim3 grid(NF * nby);

    if (ws_size >= needW) {
        f16* wsHi = (f16*)d_ws;
        f16* wsLo = wsHi + planeElems;
        presplit_w<<<NL * NF, 256, 0, stream>>>(Wh, wsHi, wsLo);
        permlp_v10<true><<<grid, dim3(NTHR), 0, stream>>>(
            x, W1, b1, Wh, bh, Wo, bo, wsHi, wsLo, out, nby);
    } else {
        permlp_v10<false><<<grid, dim3(NTHR), 0, stream>>>(
            x, W1, b1, Wh, bh, Wo, bo, nullptr, nullptr, out, nby);
    }
}

// Round 11
// 202.436 us; speedup vs baseline: 2.5561x; 1.0365x over previous
//
#include <hip/hip_runtime.h>

typedef _Float16 f16;
typedef f16    f16x2 __attribute__((ext_vector_type(2)));
typedef f16    f16x8 __attribute__((ext_vector_type(8)));
typedef __fp16 fp16x2 __attribute__((ext_vector_type(2)));
typedef float  f32x4 __attribute__((ext_vector_type(4)));

#define NF 256      // features
#define NH 64       // hidden dim
#define NL 3        // hidden-to-hidden layers
#define NB 4        // 16-row batch tiles per wave -> 64 rows/wave
#define NWAVE 4
#define MT (NB * 16 * NWAVE)   // 256 rows per block
#define NTHR (NWAVE * 64)     // 256
#define WFRAG (NH * NH)

union U2 { f16x8 v8; f16x2 h[4]; };

// sigma(p = 32ks + 8gr + j) = 32ks + 16*(j>>2) + 4gr + (j&3) baked into W
// staging: the MFMA C-tile, packed pairwise, IS the next layer's B-fragment
// (verified r9/r10). h never touches LDS; zero barriers in the main kernel.
//
// Numerics: W exact as whi+wlo (2-term, ~2^-22); h rounded once per layer
// with RTZ (cvt_pkrtz) then packed relu -> expected absmax ~6e-3 < 2.1e-2.

// pack 2 f32 -> f16x2 with RTZ, then relu in packed f16 (v_pk_max_f16)
__device__ __forceinline__ f16x2 pkmax(float a, float b) {
    fp16x2 p = __builtin_amdgcn_cvt_pkrtz(a, b);
    fp16x2 z = {(__fp16)0.f, (__fp16)0.f};
    p = __builtin_elementwise_max(p, z);
    return __builtin_bit_cast(f16x2, p);
}

// ---- prepass: split Wh into f16 hi/lo A-fragment planes with sigma baked
// ---- into the k side; coalesced f16x8 loads in the main kernel.
__global__ __launch_bounds__(256) void presplit_w(
    const float* __restrict__ Wh, f16* __restrict__ wsHi, f16* __restrict__ wsLo)
{
    __shared__ float wld[NH * NH];
    const int lf = blockIdx.x;            // l*NF + f
    const int t  = threadIdx.x;
    const float* __restrict__ src = Wh + (size_t)lf * WFRAG;
#pragma unroll
    for (int i = 0; i < 4; ++i)
        *(f32x4*)&wld[(i * 256 + t) * 4] = *(const f32x4*)&src[(i * 256 + t) * 4];
    __syncthreads();
#pragma unroll
    for (int g2 = 0; g2 < 2; ++g2) {
        const int g  = g2 * 256 + t;      // g = (mt*2+ks)*64 + ln
        const int ln = g & 63, ks = (g >> 6) & 1, mt = g >> 7;
        const int cl = ln & 15, gr = ln >> 4;
        const int m  = mt * 16 + cl;      // output unit (natural order)
        f16x8 hi, lo;
#pragma unroll
        for (int jj = 0; jj < 8; ++jj) {
            const int u = 32 * ks + 16 * (jj >> 2) + 4 * gr + (jj & 3);  // sigma
            float v = wld[u * NH + m];    // W[u][m]
            f16 h = (f16)v;
            hi[jj] = h;
            lo[jj] = (f16)(v - (float)h);
        }
        const size_t dst = ((size_t)lf * 512 + g) * 8;
        *(f16x8*)&wsHi[dst] = hi;
        *(f16x8*)&wsLo[dst] = lo;
    }
}

template <bool PRE>
__global__ __launch_bounds__(NTHR, 3) void permlp_v11(
    const float* __restrict__ x,
    const float* __restrict__ W1,
    const float* __restrict__ b1,
    const float* __restrict__ Wh,
    const float* __restrict__ bh,
    const float* __restrict__ Wo,
    const float* __restrict__ bo,
    const f16* __restrict__ wsHi,
    const f16* __restrict__ wsLo,
    float* __restrict__ out,
    int nby)
{
    // XCD-chunked bijective swizzle (nwg % 8 == 0): W working set L2-resident.
    const int nwg  = NF * nby;
    const int q    = nwg >> 3;
    const int bid  = blockIdx.x;
    const int wgid = (bid & 7) * q + (bid >> 3);
    const int f    = wgid / nby;
    const int by   = wgid - f * nby;

    const int tid = threadIdx.x;
    const int wv  = tid >> 6;
    const int ln  = tid & 63;
    const int cl  = ln & 15;
    const int gr  = ln >> 4;
    const int gb0 = by * MT + wv * (NB * 16);

    // W fragment loader (one 16x64 tile: 4 x f16x8 per lane)
    auto loadW = [&](const f16* __restrict__ baseH, const f16* __restrict__ baseL,
                     const float* __restrict__ Wl, int mt,
                     f16x8 (&Ahi)[2], f16x8 (&Alo)[2]) {
#pragma unroll
        for (int ks = 0; ks < 2; ++ks) {
            if constexpr (PRE) {
                const size_t off = (size_t)((mt * 2 + ks) * 64 + ln) * 8;
                Ahi[ks] = *(const f16x8*)&baseH[off];
                Alo[ks] = *(const f16x8*)&baseL[off];
            } else {
                const int m = mt * 16 + cl;
                f16x8 hi8, lo8;
#pragma unroll
                for (int j = 0; j < 8; ++j) {
                    const int u = 32 * ks + 16 * (j >> 2) + 4 * gr + (j & 3);
                    float v = Wl[(size_t)u * NH + m];
                    f16 h = (f16)v;
                    hi8[j] = h;
                    lo8[j] = (f16)(v - (float)h);
                }
                Ahi[ks] = hi8; Alo[ks] = lo8;
            }
        }
    };

    // ---- layer 1 straight into registers (sigma-ordered B-fragments) ----
    U2 HA[NB][2], HB[NB][2];
    {
        float xv[NB];
#pragma unroll
        for (int bt = 0; bt < NB; ++bt)
            xv[bt] = x[(size_t)(gb0 + bt * 16 + cl) * NF + f];
        const float* __restrict__ w1 = W1 + f * NH;
        const float* __restrict__ bb = b1 + f * NH;
#pragma unroll
        for (int ks = 0; ks < 2; ++ks)
#pragma unroll
            for (int jq = 0; jq < 2; ++jq) {
                const int ub = 32 * ks + 16 * jq + 4 * gr;   // sigma-ordered
                const f32x4 w4 = *(const f32x4*)&w1[ub];
                const f32x4 b4 = *(const f32x4*)&bb[ub];
#pragma unroll
                for (int bt = 0; bt < NB; ++bt) {
                    float v0 = fmaf(xv[bt], w4[0], b4[0]);
                    float v1 = fmaf(xv[bt], w4[1], b4[1]);
                    float v2 = fmaf(xv[bt], w4[2], b4[2]);
                    float v3 = fmaf(xv[bt], w4[3], b4[3]);
                    HA[bt][ks].h[jq * 2]     = pkmax(v0, v1);   // relu in pk f16
                    HA[bt][ks].h[jq * 2 + 1] = pkmax(v2, v3);
                }
            }
    }

    // ---- one hidden layer: I regs -> O regs, W double-buffered ----
    auto hidden = [&](U2 (&I)[NB][2], U2 (&O)[NB][2], const int l) {
        const f16* __restrict__ baseH = PRE ? wsHi + (size_t)(l * NF + f) * 4096 : nullptr;
        const f16* __restrict__ baseL = PRE ? wsLo + (size_t)(l * NF + f) * 4096 : nullptr;
        const float* __restrict__ Wl  = Wh + (size_t)(l * NF + f) * WFRAG;
        const float* __restrict__ bl  = bh + (size_t)(l * NF + f) * NH;
        f16x8 WHI[2][2], WLO[2][2];   // [buf][ks]
        loadW(baseH, baseL, Wl, 0, WHI[0], WLO[0]);
#pragma unroll
        for (int mt = 0; mt < 4; ++mt) {
            if (mt < 3)   // prefetch next tile while this tile computes
                loadW(baseH, baseL, Wl, mt + 1, WHI[(mt + 1) & 1], WLO[(mt + 1) & 1]);
            const f32x4 bias4 = *(const f32x4*)&bl[mt * 16 + gr * 4];
            f32x4 acc[NB];
#pragma unroll
            for (int bt = 0; bt < NB; ++bt) acc[bt] = bias4;
#pragma unroll
            for (int ks = 0; ks < 2; ++ks)
#pragma unroll
                for (int bt = 0; bt < NB; ++bt) {
                    acc[bt] = __builtin_amdgcn_mfma_f32_16x16x32_f16(WLO[mt & 1][ks], I[bt][ks].v8, acc[bt], 0, 0, 0);
                    acc[bt] = __builtin_amdgcn_mfma_f32_16x16x32_f16(WHI[mt & 1][ks], I[bt][ks].v8, acc[bt], 0, 0, 0);
                }
            // C tile (batch=cl, units mt*16+gr*4+i) -> next-layer fragment
#pragma unroll
            for (int bt = 0; bt < NB; ++bt) {
                O[bt][mt >> 1].h[(mt & 1) * 2]     = pkmax(acc[bt][0], acc[bt][1]);
                O[bt][mt >> 1].h[(mt & 1) * 2 + 1] = pkmax(acc[bt][2], acc[bt][3]);
            }
        }
    };

    hidden(HA, HB, 0);
    hidden(HB, HA, 1);

    // ---- last hidden layer with fused output dot (reads HA) ----
    float souts[NB] = {0.f, 0.f, 0.f, 0.f};
    {
        const int l = NL - 1;
        const f16* __restrict__ baseH = PRE ? wsHi + (size_t)(l * NF + f) * 4096 : nullptr;
        const f16* __restrict__ baseL = PRE ? wsLo + (size_t)(l * NF + f) * 4096 : nullptr;
        const float* __restrict__ Wl  = Wh + (size_t)(l * NF + f) * WFRAG;
        const float* __restrict__ bl  = bh + (size_t)(l * NF + f) * NH;
        f16x8 WHI[2][2], WLO[2][2];
        loadW(baseH, baseL, Wl, 0, WHI[0], WLO[0]);
#pragma unroll
        for (int mt = 0; mt < 4; ++mt) {
            if (mt < 3)
                loadW(baseH, baseL, Wl, mt + 1, WHI[(mt + 1) & 1], WLO[(mt + 1) & 1]);
            const f32x4 bias4 = *(const f32x4*)&bl[mt * 16 + gr * 4];
            f32x4 acc[NB];
#pragma unroll
            for (int bt = 0; bt < NB; ++bt) acc[bt] = bias4;
#pragma unroll
            for (int ks = 0; ks < 2; ++ks)
#pragma unroll
                for (int bt = 0; bt < NB; ++bt) {
                    acc[bt] = __builtin_amdgcn_mfma_f32_16x16x32_f16(WLO[mt & 1][ks], HA[bt][ks].v8, acc[bt], 0, 0, 0);
                    acc[bt] = __builtin_amdgcn_mfma_f32_16x16x32_f16(WHI[mt & 1][ks], HA[bt][ks].v8, acc[bt], 0, 0, 0);
                }
            const f32x4 wov4 = *(const f32x4*)&Wo[f * NH + mt * 16 + gr * 4];
#pragma unroll
            for (int bt = 0; bt < NB; ++bt)
#pragma unroll
                for (int i = 0; i < 4; ++i)
                    souts[bt] = fmaf(fmaxf(acc[bt][i], 0.f), wov4[i], souts[bt]);
        }
    }

    // ---- commit: reduce over gr-groups, one atomic per row ----
    const float bof = bo[f];
#pragma unroll
    for (int bt = 0; bt < NB; ++bt) {
        float s = souts[bt];
        s += __shfl_xor(s, 16, 64);
        s += __shfl_xor(s, 32, 64);
        if (ln < 16)
            atomicAdd(&out[gb0 + bt * 16 + ln], s + bof);
    }
}

extern "C" void kernel_launch(void* const* d_in, const int* in_sizes, int n_in,
                              void* d_out, int out_size, void* d_ws, size_t ws_size,
                              hipStream_t stream)
{
    const float* x  = (const float*)d_in[0];
    const float* W1 = (const float*)d_in[1];
    const float* b1 = (const float*)d_in[2];
    const float* Wh = (const float*)d_in[3];
    const float* bh = (const float*)d_in[4];
    const float* Wo = (const float*)d_in[5];
    const float* bo = (const float*)d_in[6];
    float* out = (float*)d_out;

    const int B   = in_sizes[0] / NF;   // 16384
    const int nby = B / MT;             // 64

    hipMemsetAsync(out, 0, (size_t)out_size * sizeof(float), stream);

    const size_t planeElems = (size_t)NL * NF * WFRAG;          // 3.15M f16
    const size_t needW      = planeElems * 2 * sizeof(f16);     // ~12.6 MB
    dim3 grid(NF * nby);

    if (ws_size >= needW) {
        f16* wsHi = (f16*)d_ws;
        f16* wsLo = wsHi + planeElems;
        presplit_w<<<NL * NF, 256, 0, stream>>>(Wh, wsHi, wsLo);
        permlp_v11<true><<<grid, dim3(NTHR), 0, stream>>>(
            x, W1, b1, Wh, bh, Wo, bo, wsHi, wsLo, out, nby);
    } else {
        permlp_v11<false><<<grid, dim3(NTHR), 0, stream>>>(
            x, W1, b1, Wh, bh, Wo, bo, nullptr, nullptr, out, nby);
    }
}